// Round 9
// baseline (1143.109 us; speedup 1.0000x reference)
//
#include <hip/hip_runtime.h>
#include <hip/hip_bf16.h>
#include <stdint.h>

typedef __bf16 bf16;
typedef bf16 bf16x8 __attribute__((ext_vector_type(8)));
typedef bf16 bf16x2 __attribute__((ext_vector_type(2)));
typedef float f32x4 __attribute__((ext_vector_type(4)));

__device__ __forceinline__ float b2f(bf16 x) {
  unsigned short u = __builtin_bit_cast(unsigned short, x);
  unsigned int v = ((unsigned int)u) << 16;
  return __builtin_bit_cast(float, v);
}
__device__ __forceinline__ bf16 f2b(float f) {
  unsigned int u = __builtin_bit_cast(unsigned int, f);
  unsigned int r = (u + 0x7FFFu + ((u >> 16) & 1u)) >> 16;
  return __builtin_bit_cast(bf16, (unsigned short)r);
}

__device__ __forceinline__ void async_copy16(const bf16* g, bf16* l) {
  __builtin_amdgcn_global_load_lds(
      (const __attribute__((address_space(1))) void*)g,
      (__attribute__((address_space(3))) void*)l, 16, 0, 0);
}

// ---------------- GEMM: C = A(Mx512)*B(512xN) + bias, all geometry compile-time.
// BT = B transposed (N x 512 bf16). Block tile (MFR*32)x128, BK=64, XOR-swizzled LDS.
// 4 waves as 2x2; wave tile (MFR*16)x64. MFR=6: cap ~45% MfmaUtil, 3 waves/SIMD.
// SWZ: supergroup remap (8 m-tiles x all n-tiles contiguous) for L2/A-reuse.
template <int MFR, int LDA, int LDC, int RSTR, bool RELU, bool RESID, bool RAWG, bool F32OUT, bool SWZ>
__global__ __launch_bounds__(256, (MFR == 6 ? 3 : 4)) void gemm_kernel(
    const bf16* __restrict__ A,
    const bf16* __restrict__ BT,
    const float* __restrict__ bias,
    const bf16* __restrict__ resid,
    const float* __restrict__ rawg,
    bf16* __restrict__ Cb, float* __restrict__ Cf)
{
  constexpr int K = 512;
  constexpr int MROWS = MFR * 32;
  __shared__ bf16 As[MROWS * 64];
  __shared__ bf16 Bs[128 * 64];
  const int t = threadIdx.x;
  const int lane = t & 63;
  const int wave = t >> 6;

  int bx, by;
  if (SWZ) {
    const int gn = gridDim.x, gm = gridDim.y;
    int id = blockIdx.y * gn + blockIdx.x;
    int full = (gm & ~7) * gn;
    if (id < full) {
      int sg = id / (8 * gn);
      int r = id - sg * (8 * gn);
      by = sg * 8 + (r & 7);
      bx = r >> 3;
    } else {
      int r = id - full;
      int rem = gm - (gm & ~7);
      by = (gm & ~7) + (r % rem);
      bx = r / rem;
    }
  } else {
    bx = blockIdx.x; by = blockIdx.y;
  }

  const long m0 = (long)by * MROWS;
  const int n0 = bx * 128;
  const int wm = (wave >> 1) * (MFR * 16);
  const int wn = (wave & 1) * 64;
  const int row16 = lane & 15;
  const int quad = lane >> 4;

  f32x4 acc[MFR][4] = {};

  const bf16* gA[MFR]; const bf16* gB[4];
  bf16* lA[MFR]; bf16* lB[4];
#pragma unroll
  for (int i = 0; i < MFR; i++) {
    int c = i * 256 + t;
    int row = c >> 3;
    int kc = (c & 7) ^ (row & 7);
    gA[i] = A + (m0 + row) * LDA + kc * 8;
    lA[i] = As + i * 2048 + wave * 512;
  }
#pragma unroll
  for (int i = 0; i < 4; i++) {
    int c = i * 256 + t;
    int row = c >> 3;
    int kc = (c & 7) ^ (row & 7);
    gB[i] = BT + (long)(n0 + row) * K + kc * 8;
    lB[i] = Bs + i * 2048 + wave * 512;
  }

  const int rb7 = row16 & 7;
  const bf16* paA = As + (wm + row16) * 64;
  const bf16* pbB = Bs + (wn + row16) * 64;
  const int o0 = ((0 + quad) ^ rb7) * 8;
  const int o1 = ((4 + quad) ^ rb7) * 8;

#pragma unroll 1
  for (int kt = 0; kt < K; kt += 64) {
#pragma unroll
    for (int i = 0; i < MFR; i++) async_copy16(gA[i] + kt, lA[i]);
#pragma unroll
    for (int i = 0; i < 4; i++) async_copy16(gB[i] + kt, lB[i]);
    __syncthreads();
    {
      bf16x8 af[MFR], bfr[4];
#pragma unroll
      for (int i = 0; i < MFR; i++) af[i] = *(const bf16x8*)(paA + i * 1024 + o0);
#pragma unroll
      for (int i = 0; i < 4; i++) bfr[i] = *(const bf16x8*)(pbB + i * 1024 + o0);
#pragma unroll
      for (int mi = 0; mi < MFR; mi++)
#pragma unroll
        for (int ni = 0; ni < 4; ni++)
          acc[mi][ni] = __builtin_amdgcn_mfma_f32_16x16x32_bf16(af[mi], bfr[ni], acc[mi][ni], 0, 0, 0);
    }
    {
      bf16x8 af[MFR], bfr[4];
#pragma unroll
      for (int i = 0; i < MFR; i++) af[i] = *(const bf16x8*)(paA + i * 1024 + o1);
#pragma unroll
      for (int i = 0; i < 4; i++) bfr[i] = *(const bf16x8*)(pbB + i * 1024 + o1);
#pragma unroll
      for (int mi = 0; mi < MFR; mi++)
#pragma unroll
        for (int ni = 0; ni < 4; ni++)
          acc[mi][ni] = __builtin_amdgcn_mfma_f32_16x16x32_bf16(af[mi], bfr[ni], acc[mi][ni], 0, 0, 0);
    }
    __syncthreads();
  }

  float bv[4];
#pragma unroll
  for (int ni = 0; ni < 4; ni++) bv[ni] = bias[n0 + wn + ni * 16 + row16];
#pragma unroll
  for (int mi = 0; mi < MFR; mi++) {
    long rb = m0 + wm + mi * 16 + quad * 4;
#pragma unroll
    for (int ni = 0; ni < 4; ni++) {
      int col = n0 + wn + ni * 16 + row16;
#pragma unroll
      for (int r = 0; r < 4; r++) {
        float xv = acc[mi][ni][r] + bv[ni];
        if (RESID) xv += b2f(resid[(rb + r) * RSTR + col]);
        if (RELU) xv = fmaxf(xv, 0.f);
        if (RAWG) xv = rawg[(rb + r) * 512 + col] * (1.f + fmaxf(xv, 0.f));
        if (F32OUT) Cf[(rb + r) * LDC + col] = xv;
        else        Cb[(rb + r) * LDC + col] = f2b(xv);
      }
    }
  }
}

// ---------------- Fused GEMM + residual + LayerNorm.
// C = LN(A(Mx512) @ B(512x512) + bias + resid) * g + b.  Block: 64 rows x FULL 512 cols,
// 4 waves 1x4 (wave 64x128), BK=32. B-tile 512x32 LDS (32KB) + A 4KB. Whole row in-block
// -> LN stats via shfl + cross-wave LDS reduce (reuses As). 2 blocks/CU.
template <int LDA, int RSTR, int LDC>
__global__ __launch_bounds__(256, 2) void gemm_ln_kernel(
    const bf16* __restrict__ A,
    const bf16* __restrict__ BT,
    const float* __restrict__ bias,
    const bf16* __restrict__ resid,
    const float* __restrict__ g,
    const float* __restrict__ b,
    bf16* __restrict__ C)
{
  constexpr int K = 512;
  __shared__ bf16 As[64 * 32];    // 4 KB
  __shared__ bf16 Bs[512 * 32];   // 32 KB
  const int t = threadIdx.x;
  const int lane = t & 63;
  const int wave = t >> 6;
  const long m0 = (long)blockIdx.x * 64;
  const int wn = wave * 128;
  const int row16 = lane & 15;
  const int quad = lane >> 4;

  f32x4 acc[4][8] = {};

  // A staging: 64 rows x 4 chunks = 256; thread t owns chunk t.
  const int rowA = t >> 2;
  const int kcA = (t & 3) ^ ((rowA >> 1) & 3);
  const bf16* gA = A + (m0 + rowA) * LDA + kcA * 8;
  bf16* lA = As + wave * 512;
  // B staging: 512 rows x 4 chunks = 2048; thread owns c = i*256+t.
  const int rB0 = t >> 2;
  const int kcB = (t & 3) ^ ((rB0 >> 1) & 3);   // i*64 adds nothing to bits 1..2 of row>>1
  const bf16* gB[8];
  bf16* lB[8];
#pragma unroll
  for (int i = 0; i < 8; i++) {
    gB[i] = BT + (long)(i * 64 + rB0) * K + kcB * 8;
    lB[i] = Bs + i * 2048 + wave * 512;
  }

  const int sw = (row16 >> 1) & 3;
  const int ofs = (quad ^ sw) * 8;
  const bf16* pa = As + row16 * 32 + ofs;
  const bf16* pb = Bs + (wn + row16) * 32 + ofs;

#pragma unroll 1
  for (int kt = 0; kt < K; kt += 32) {
    async_copy16(gA + kt, lA);
#pragma unroll
    for (int i = 0; i < 8; i++) async_copy16(gB[i] + kt, lB[i]);
    __syncthreads();
    bf16x8 af[4], bfr[8];
#pragma unroll
    for (int i = 0; i < 4; i++) af[i] = *(const bf16x8*)(pa + i * 512);
#pragma unroll
    for (int i = 0; i < 8; i++) bfr[i] = *(const bf16x8*)(pb + i * 512);
#pragma unroll
    for (int mi = 0; mi < 4; mi++)
#pragma unroll
      for (int ni = 0; ni < 8; ni++)
        acc[mi][ni] = __builtin_amdgcn_mfma_f32_16x16x32_bf16(af[mi], bfr[ni], acc[mi][ni], 0, 0, 0);
    __syncthreads();
  }

  // epilogue: bias + resid, per-row mean/var over all 512 cols, LN, write.
  float bsv[8], gv[8], bvv[8];
  int cols[8];
#pragma unroll
  for (int ni = 0; ni < 8; ni++) {
    cols[ni] = wn + ni * 16 + row16;
    bsv[ni] = bias[cols[ni]];
    gv[ni] = g[cols[ni]];
    bvv[ni] = b[cols[ni]];
  }
  float* redS = (float*)As;        // [64][4]
  float* redQ = redS + 256;        // [64][4]
#pragma unroll
  for (int mi = 0; mi < 4; mi++) {
#pragma unroll
    for (int r = 0; r < 4; r++) {
      const int lrow = mi * 16 + quad * 4 + r;
      const long grow = m0 + lrow;
      float s = 0.f, q = 0.f;
#pragma unroll
      for (int ni = 0; ni < 8; ni++) {
        float val = acc[mi][ni][r] + bsv[ni] + b2f(resid[grow * RSTR + cols[ni]]);
        acc[mi][ni][r] = val;
        s += val;
        q += val * val;
      }
#pragma unroll
      for (int off = 1; off < 16; off <<= 1) {
        s += __shfl_xor(s, off);
        q += __shfl_xor(q, off);
      }
      if (row16 == 0) { redS[lrow * 4 + wave] = s; redQ[lrow * 4 + wave] = q; }
    }
  }
  __syncthreads();
#pragma unroll
  for (int mi = 0; mi < 4; mi++) {
#pragma unroll
    for (int r = 0; r < 4; r++) {
      const int lrow = mi * 16 + quad * 4 + r;
      const long grow = m0 + lrow;
      float S = redS[lrow * 4] + redS[lrow * 4 + 1] + redS[lrow * 4 + 2] + redS[lrow * 4 + 3];
      float Q = redQ[lrow * 4] + redQ[lrow * 4 + 1] + redQ[lrow * 4 + 2] + redQ[lrow * 4 + 3];
      float mean = S * (1.f / 512.f);
      float inv = rsqrtf(Q * (1.f / 512.f) - mean * mean + 1e-5f);
#pragma unroll
      for (int ni = 0; ni < 8; ni++) {
        float o = (acc[mi][ni][r] - mean) * inv * gv[ni] + bvv[ni];
        C[grow * LDC + cols[ni]] = f2b(o);
      }
    }
  }
}

// ---------------- attention: per-sequence (S=9, H=8, HD=64), bf16 LDS staging.
// Reads qkv rows (stride 1536 bf16); writes ctx IN-PLACE into cols [0,512).
#define ROWP 520
__global__ __launch_bounds__(512) void attn_kernel(bf16* __restrict__ qkv)
{
  __shared__ bf16 q[9 * ROWP];
  __shared__ bf16 k[9 * ROWP];
  __shared__ bf16 v[9 * ROWP];
  __shared__ float sc[8 * 81];
  const long n = blockIdx.x;
  const int t = threadIdx.x;
  bf16* base = qkv + n * (9 * 1536);
  for (int c = t; c < 1728; c += 512) {
    int o = c * 8;
    int s = o / 1536;
    int col = o - s * 1536;
    bf16x8 rawv = *(const bf16x8*)(base + o);
    bf16* dst;
    int cc;
    if (col < 512)       { dst = q; cc = col; }
    else if (col < 1024) { dst = k; cc = col - 512; }
    else                 { dst = v; cc = col - 1024; }
    *(bf16x8*)(dst + s * ROWP + cc) = rawv;
  }
  __syncthreads();
  for (int id = t; id < 648; id += 512) {
    int h = id / 81;
    int r = id - h * 81;
    int si = r / 9;
    int sj = r - si * 9;
    const bf16* qp = q + si * ROWP + h * 64;
    const bf16* kp = k + sj * ROWP + h * 64;
    float acc = 0.f;
#pragma unroll
    for (int j = 0; j < 64; j += 8) {
      bf16x8 qa = *(const bf16x8*)(qp + j);
      bf16x8 ka = *(const bf16x8*)(kp + j);
#pragma unroll
      for (int u = 0; u < 8; u++) acc += b2f(qa[u]) * b2f(ka[u]);
    }
    sc[h * 81 + si * 9 + sj] = acc * 0.125f;
  }
  __syncthreads();
  if (t < 72) {
    int h = t / 9, si = t - h * 9;
    float* row = sc + h * 81 + si * 9;
    float m = row[0];
    for (int j = 1; j < 9; j++) m = fmaxf(m, row[j]);
    float s = 0.f;
    float e[9];
    for (int j = 0; j < 9; j++) { e[j] = __expf(row[j] - m); s += e[j]; }
    float inv = 1.f / s;
    for (int j = 0; j < 9; j++) row[j] = e[j] * inv;
  }
  __syncthreads();
  for (int e2 = t; e2 < 2304; e2 += 512) {
    int si = e2 >> 8;
    int c2 = (e2 & 255) * 2;
    int h = c2 >> 6;
    const float* ar = sc + h * 81 + si * 9;
    float a0 = 0.f, a1 = 0.f;
#pragma unroll
    for (int sj = 0; sj < 9; sj++) {
      bf16x2 vv = *(const bf16x2*)(v + sj * ROWP + c2);
      float w = ar[sj];
      a0 += w * b2f(vv[0]);
      a1 += w * b2f(vv[1]);
    }
    bf16x2 o;
    o[0] = f2b(a0); o[1] = f2b(a1);
    *(bf16x2*)(base + si * 1536 + c2) = o;
  }
}

// ---------------- embedding gather: h[row](bf16) = adapt_w[x[row]] + adapt_b  (fp32 in)
__global__ __launch_bounds__(256) void emb_kernel(const int* __restrict__ x, const float* __restrict__ aw,
                                                  const float* __restrict__ ab, bf16* __restrict__ h)
{
  const int t = threadIdx.x;
  const int lane = t & 63;
  const long row = (long)blockIdx.x * 4 + (t >> 6);
  const int ix = x[row];
  const float* w = aw + (long)ix * 512 + lane * 8;
  float4 w0 = *(const float4*)(w);
  float4 w1 = *(const float4*)(w + 4);
  float4 a0 = *(const float4*)(ab + lane * 8);
  float4 a1 = *(const float4*)(ab + lane * 8 + 4);
  float ww[8] = {w0.x, w0.y, w0.z, w0.w, w1.x, w1.y, w1.z, w1.w};
  float aa[8] = {a0.x, a0.y, a0.z, a0.w, a1.x, a1.y, a1.z, a1.w};
  bf16x8 o;
#pragma unroll
  for (int j = 0; j < 8; j++) o[j] = f2b(ww[j] + aa[j]);
  *(bf16x8*)(h + row * 512 + lane * 8) = o;
}

// ---------------- raw_emb (fp32): per (b,t): sum_s adapt2_w[s*E + x[n,s]] + adapt2_b
__global__ __launch_bounds__(256) void rawemb_kernel(const int* __restrict__ x, const float* __restrict__ w2,
                                                     const float* __restrict__ b2, float* __restrict__ raw)
{
  const long n = blockIdx.x;
  const int t = threadIdx.x;
  const int c = t * 2;
  float a0 = b2[c], a1 = b2[c + 1];
  for (int s = 0; s < 9; s++) {
    int ix = x[n * 9 + s];
    const float* p = w2 + ((long)(s * 631 + ix)) * 512 + c;
    a0 += p[0];
    a1 += p[1];
  }
  raw[n * 512 + c] = a0;
  raw[n * 512 + c + 1] = a1;
}

// ---------------- batched weight transpose+cast: fp32 (512 x N) -> bf16 (N x 512)
struct TP { const float* src[9]; bf16* dst[9]; int n[9]; };
__global__ __launch_bounds__(256) void transpose_kernel(TP p)
{
  const int mid = blockIdx.z;
  const int N = p.n[mid];
  if ((int)blockIdx.x * 32 >= N) return;
  const float* src = p.src[mid];
  bf16* dst = p.dst[mid];
  __shared__ float tile[32][33];
  const int tx = threadIdx.x & 31;
  const int ty0 = (threadIdx.x >> 5) * 4;
  const long kb = (long)blockIdx.y * 32, nb = (long)blockIdx.x * 32;
#pragma unroll
  for (int i = 0; i < 4; i++) tile[ty0 + i][tx] = src[(kb + ty0 + i) * N + nb + tx];
  __syncthreads();
#pragma unroll
  for (int i = 0; i < 4; i++) dst[(nb + ty0 + i) * 512 + kb + tx] = f2b(tile[tx][ty0 + i]);
}

extern "C" void kernel_launch(void* const* d_in, const int* in_sizes, int n_in,
                              void* d_out, int out_size, void* d_ws, size_t ws_size,
                              hipStream_t stream)
{
  (void)in_sizes; (void)n_in; (void)out_size;
  const int*   x        = (const int*)d_in[0];
  const float* adapt2_w = (const float*)d_in[1];
  const float* adapt2_b = (const float*)d_in[2];
  const float* adapt_w  = (const float*)d_in[3];
  const float* adapt_b  = (const float*)d_in[4];
  const float* qkv_w    = (const float*)d_in[5];
  const float* qkv_b    = (const float*)d_in[6];
  const float* out_w    = (const float*)d_in[7];
  const float* out_b    = (const float*)d_in[8];
  const float* ln1_g    = (const float*)d_in[9];
  const float* ln1_b    = (const float*)d_in[10];
  const float* lin1_w   = (const float*)d_in[11];
  const float* lin1_b   = (const float*)d_in[12];
  const float* lin2_w   = (const float*)d_in[13];
  const float* lin2_b   = (const float*)d_in[14];
  const float* ln2_g    = (const float*)d_in[15];
  const float* ln2_b    = (const float*)d_in[16];
  const float* fc_w     = (const float*)d_in[17];
  const float* fc_b     = (const float*)d_in[18];
  float* outp = (float*)d_out;
  char* ws = (char*)d_ws;

  // ---- choose chunking G from ws_size (deterministic -> graph-safe)
  const long wTbytes = 6815744L;  // bf16 transposed weights
  int G = 64;
  const int cand[7] = {1, 2, 4, 8, 16, 32, 64};
  for (int i = 0; i < 7; i++) {
    long rows = 73728L / cand[i], seqs = 8192L / cand[i];
    long need = wTbytes + rows * 1024 + rows * 3072 + seqs * 2048;
    if (need <= (long)ws_size) { G = cand[i]; break; }
  }
  const long rows_c = 73728L / G;   // divisible by 192 and 64 for all candidate G
  const long seqs_c = 8192L / G;

  // ---- workspace layout
  bf16*  wT    = (bf16*)(ws);
  bf16*  h_c   = (bf16*)(ws + wTbytes);                                  // rows_c x 512 bf16
  bf16*  Qc    = (bf16*)(ws + wTbytes + rows_c * 1024);                  // rows_c x 1536 bf16
  float* raw_c = (float*)(ws + wTbytes + rows_c * 1024 + rows_c * 3072); // seqs_c x 512 fp32
  bf16* qkvT  = wT;                 // 2 x (1536 x 512)
  bf16* outT  = wT + 1572864;       // 2 x (512 x 512)
  bf16* lin1T = wT + 2097152;
  bf16* lin2T = wT + 2621440;
  bf16* fcT   = wT + 3145728;       // 512 x 512

  TP tp;
  tp.src[0] = qkv_w;           tp.dst[0] = qkvT;           tp.n[0] = 1536;
  tp.src[1] = qkv_w + 786432;  tp.dst[1] = qkvT + 786432;  tp.n[1] = 1536;
  tp.src[2] = out_w;           tp.dst[2] = outT;           tp.n[2] = 512;
  tp.src[3] = out_w + 262144;  tp.dst[3] = outT + 262144;  tp.n[3] = 512;
  tp.src[4] = lin1_w;          tp.dst[4] = lin1T;          tp.n[4] = 512;
  tp.src[5] = lin1_w + 262144; tp.dst[5] = lin1T + 262144; tp.n[5] = 512;
  tp.src[6] = lin2_w;          tp.dst[6] = lin2T;          tp.n[6] = 512;
  tp.src[7] = lin2_w + 262144; tp.dst[7] = lin2T + 262144; tp.n[7] = 512;
  tp.src[8] = fc_w;            tp.dst[8] = fcT;            tp.n[8] = 512;
  hipLaunchKernelGGL(transpose_kernel, dim3(48, 16, 9), dim3(256), 0, stream, tp);

  const bf16*  nullb = nullptr;
  const float* nullf = nullptr;
  float*       nullfo = nullptr;

  for (int g = 0; g < G; g++) {
    const long row0 = (long)g * rows_c;
    const long seq0 = (long)g * seqs_c;

    hipLaunchKernelGGL(emb_kernel, dim3(rows_c / 4), dim3(256), 0, stream,
        x + row0, adapt_w, adapt_b, h_c);
    hipLaunchKernelGGL(rawemb_kernel, dim3(seqs_c), dim3(256), 0, stream,
        x + seq0 * 9, adapt2_w, adapt2_b, raw_c);

    for (int l = 0; l < 2; l++) {
      // qkv = h @ qkv_w + qkv_b  -> Qc (rows_c x 1536)
      hipLaunchKernelGGL((gemm_kernel<6, 512, 1536, 1, false, false, false, false, true>),
          dim3(12, rows_c / 192), dim3(256), 0, stream,
          h_c, qkvT + l * 786432, qkv_b + l * 1536, nullb, nullf, Qc, nullfo);
      // attention in-place: ctx -> Qc cols [0,512)
      hipLaunchKernelGGL(attn_kernel, dim3(seqs_c), dim3(512), 0, stream, Qc);
      // h1 = LN1(ctx @ out_w + out_b + h) -> Qc cols [512,1024)   [fused GEMM+LN]
      hipLaunchKernelGGL((gemm_ln_kernel<1536, 512, 1536>),
          dim3(rows_c / 64), dim3(256), 0, stream,
          Qc, outT + l * 262144, out_b + l * 512, h_c,
          ln1_g + l * 512, ln1_b + l * 512, Qc + 512);
      // ff1 = relu(h1 @ lin1_w + lin1_b) -> Qc cols [0,512)
      hipLaunchKernelGGL((gemm_kernel<6, 1536, 1536, 1, true, false, false, false, true>),
          dim3(4, rows_c / 192), dim3(256), 0, stream,
          Qc + 512, lin1T + l * 262144, lin1_b + l * 512, nullb, nullf, Qc, nullfo);
      // h = LN2(ff1 @ lin2_w + lin2_b + h1) -> h_c   [fused GEMM+LN]
      hipLaunchKernelGGL((gemm_ln_kernel<1536, 1536, 512>),
          dim3(rows_c / 64), dim3(256), 0, stream,
          Qc, lin2T + l * 262144, lin2_b + l * 512, Qc + 512,
          ln2_g + l * 512, ln2_b + l * 512, h_c);
    }

    // out(fp32) = raw * (1 + relu(cls @ fc_w + fc_b)); cls rows at stride 4608 in h_c
    hipLaunchKernelGGL((gemm_kernel<4, 4608, 512, 1, false, false, true, true, false>),
        dim3(4, seqs_c / 128), dim3(256), 0, stream,
        h_c, fcT, fc_b, nullb, raw_c, (bf16*)nullptr, outp + seq0 * 512);
  }
}

// Round 10
// 997.352 us; speedup vs baseline: 1.1461x; 1.1461x over previous
//
#include <hip/hip_runtime.h>
#include <hip/hip_bf16.h>
#include <stdint.h>

typedef __bf16 bf16;
typedef bf16 bf16x8 __attribute__((ext_vector_type(8)));
typedef bf16 bf16x2 __attribute__((ext_vector_type(2)));
typedef float f32x4 __attribute__((ext_vector_type(4)));

__device__ __forceinline__ float b2f(bf16 x) {
  unsigned short u = __builtin_bit_cast(unsigned short, x);
  unsigned int v = ((unsigned int)u) << 16;
  return __builtin_bit_cast(float, v);
}
__device__ __forceinline__ bf16 f2b(float f) {
  unsigned int u = __builtin_bit_cast(unsigned int, f);
  unsigned int r = (u + 0x7FFFu + ((u >> 16) & 1u)) >> 16;
  return __builtin_bit_cast(bf16, (unsigned short)r);
}

__device__ __forceinline__ void async_copy16(const bf16* g, bf16* l) {
  __builtin_amdgcn_global_load_lds(
      (const __attribute__((address_space(1))) void*)g,
      (__attribute__((address_space(3))) void*)l, 16, 0, 0);
}

// ---------------- GEMM: C = A(Mx512)*B(512xN) + bias, all geometry compile-time.
// BT = B transposed (N x 512 bf16). Block tile (MFR*32)x128, BK=64, XOR-swizzled LDS.
// 4 waves as 2x2; wave tile (MFR*16)x64. MFR=6: 2 waves/SIMD (176 regs incl acc).
// SWZ: supergroup remap (8 m-tiles x all n-tiles contiguous) for L2/A-reuse.
template <int MFR, int LDA, int LDC, int RSTR, bool RELU, bool RESID, bool RAWG, bool F32OUT, bool SWZ>
__global__ __launch_bounds__(256, (MFR == 6 ? 2 : 4)) void gemm_kernel(
    const bf16* __restrict__ A,
    const bf16* __restrict__ BT,
    const float* __restrict__ bias,
    const bf16* __restrict__ resid,
    const float* __restrict__ rawg,
    bf16* __restrict__ Cb, float* __restrict__ Cf)
{
  constexpr int K = 512;
  constexpr int MROWS = MFR * 32;
  __shared__ bf16 As[MROWS * 64];
  __shared__ bf16 Bs[128 * 64];
  const int t = threadIdx.x;
  const int lane = t & 63;
  const int wave = t >> 6;

  int bx, by;
  if (SWZ) {
    const int gn = gridDim.x, gm = gridDim.y;
    int id = blockIdx.y * gn + blockIdx.x;
    int full = (gm & ~7) * gn;
    if (id < full) {
      int sg = id / (8 * gn);
      int r = id - sg * (8 * gn);
      by = sg * 8 + (r & 7);
      bx = r >> 3;
    } else {
      int r = id - full;
      int rem = gm - (gm & ~7);
      by = (gm & ~7) + (r % rem);
      bx = r / rem;
    }
  } else {
    bx = blockIdx.x; by = blockIdx.y;
  }

  const long m0 = (long)by * MROWS;
  const int n0 = bx * 128;
  const int wm = (wave >> 1) * (MFR * 16);
  const int wn = (wave & 1) * 64;
  const int row16 = lane & 15;
  const int quad = lane >> 4;

  f32x4 acc[MFR][4] = {};

  const bf16* gA[MFR]; const bf16* gB[4];
  bf16* lA[MFR]; bf16* lB[4];
#pragma unroll
  for (int i = 0; i < MFR; i++) {
    int c = i * 256 + t;
    int row = c >> 3;
    int kc = (c & 7) ^ (row & 7);
    gA[i] = A + (m0 + row) * LDA + kc * 8;
    lA[i] = As + i * 2048 + wave * 512;
  }
#pragma unroll
  for (int i = 0; i < 4; i++) {
    int c = i * 256 + t;
    int row = c >> 3;
    int kc = (c & 7) ^ (row & 7);
    gB[i] = BT + (long)(n0 + row) * K + kc * 8;
    lB[i] = Bs + i * 2048 + wave * 512;
  }

  const int rb7 = row16 & 7;
  const bf16* paA = As + (wm + row16) * 64;
  const bf16* pbB = Bs + (wn + row16) * 64;
  const int o0 = ((0 + quad) ^ rb7) * 8;
  const int o1 = ((4 + quad) ^ rb7) * 8;

#pragma unroll 1
  for (int kt = 0; kt < K; kt += 64) {
#pragma unroll
    for (int i = 0; i < MFR; i++) async_copy16(gA[i] + kt, lA[i]);
#pragma unroll
    for (int i = 0; i < 4; i++) async_copy16(gB[i] + kt, lB[i]);
    __syncthreads();
    {
      bf16x8 af[MFR], bfr[4];
#pragma unroll
      for (int i = 0; i < MFR; i++) af[i] = *(const bf16x8*)(paA + i * 1024 + o0);
#pragma unroll
      for (int i = 0; i < 4; i++) bfr[i] = *(const bf16x8*)(pbB + i * 1024 + o0);
#pragma unroll
      for (int mi = 0; mi < MFR; mi++)
#pragma unroll
        for (int ni = 0; ni < 4; ni++)
          acc[mi][ni] = __builtin_amdgcn_mfma_f32_16x16x32_bf16(af[mi], bfr[ni], acc[mi][ni], 0, 0, 0);
    }
    {
      bf16x8 af[MFR], bfr[4];
#pragma unroll
      for (int i = 0; i < MFR; i++) af[i] = *(const bf16x8*)(paA + i * 1024 + o1);
#pragma unroll
      for (int i = 0; i < 4; i++) bfr[i] = *(const bf16x8*)(pbB + i * 1024 + o1);
#pragma unroll
      for (int mi = 0; mi < MFR; mi++)
#pragma unroll
        for (int ni = 0; ni < 4; ni++)
          acc[mi][ni] = __builtin_amdgcn_mfma_f32_16x16x32_bf16(af[mi], bfr[ni], acc[mi][ni], 0, 0, 0);
    }
    __syncthreads();
  }

  float bv[4];
#pragma unroll
  for (int ni = 0; ni < 4; ni++) bv[ni] = bias[n0 + wn + ni * 16 + row16];
#pragma unroll
  for (int mi = 0; mi < MFR; mi++) {
    long rb = m0 + wm + mi * 16 + quad * 4;
#pragma unroll
    for (int ni = 0; ni < 4; ni++) {
      int col = n0 + wn + ni * 16 + row16;
#pragma unroll
      for (int r = 0; r < 4; r++) {
        float xv = acc[mi][ni][r] + bv[ni];
        if (RESID) xv += b2f(resid[(rb + r) * RSTR + col]);
        if (RELU) xv = fmaxf(xv, 0.f);
        if (RAWG) xv = rawg[(rb + r) * 512 + col] * (1.f + fmaxf(xv, 0.f));
        if (F32OUT) Cf[(rb + r) * LDC + col] = xv;
        else        Cb[(rb + r) * LDC + col] = f2b(xv);
      }
    }
  }
}

// ---------------- attention: per-sequence (S=9, H=8, HD=64), bf16 LDS staging.
// Reads qkv rows (stride 1536 bf16); writes ctx IN-PLACE into cols [0,512).
#define ROWP 520
__global__ __launch_bounds__(512) void attn_kernel(bf16* __restrict__ qkv)
{
  __shared__ bf16 q[9 * ROWP];
  __shared__ bf16 k[9 * ROWP];
  __shared__ bf16 v[9 * ROWP];
  __shared__ float sc[8 * 81];
  const long n = blockIdx.x;
  const int t = threadIdx.x;
  bf16* base = qkv + n * (9 * 1536);
  for (int c = t; c < 1728; c += 512) {
    int o = c * 8;
    int s = o / 1536;
    int col = o - s * 1536;
    bf16x8 rawv = *(const bf16x8*)(base + o);
    bf16* dst;
    int cc;
    if (col < 512)       { dst = q; cc = col; }
    else if (col < 1024) { dst = k; cc = col - 512; }
    else                 { dst = v; cc = col - 1024; }
    *(bf16x8*)(dst + s * ROWP + cc) = rawv;
  }
  __syncthreads();
  for (int id = t; id < 648; id += 512) {
    int h = id / 81;
    int r = id - h * 81;
    int si = r / 9;
    int sj = r - si * 9;
    const bf16* qp = q + si * ROWP + h * 64;
    const bf16* kp = k + sj * ROWP + h * 64;
    float acc = 0.f;
#pragma unroll
    for (int j = 0; j < 64; j += 8) {
      bf16x8 qa = *(const bf16x8*)(qp + j);
      bf16x8 ka = *(const bf16x8*)(kp + j);
#pragma unroll
      for (int u = 0; u < 8; u++) acc += b2f(qa[u]) * b2f(ka[u]);
    }
    sc[h * 81 + si * 9 + sj] = acc * 0.125f;
  }
  __syncthreads();
  if (t < 72) {
    int h = t / 9, si = t - h * 9;
    float* row = sc + h * 81 + si * 9;
    float m = row[0];
    for (int j = 1; j < 9; j++) m = fmaxf(m, row[j]);
    float s = 0.f;
    float e[9];
    for (int j = 0; j < 9; j++) { e[j] = __expf(row[j] - m); s += e[j]; }
    float inv = 1.f / s;
    for (int j = 0; j < 9; j++) row[j] = e[j] * inv;
  }
  __syncthreads();
  for (int e2 = t; e2 < 2304; e2 += 512) {
    int si = e2 >> 8;
    int c2 = (e2 & 255) * 2;
    int h = c2 >> 6;
    const float* ar = sc + h * 81 + si * 9;
    float a0 = 0.f, a1 = 0.f;
#pragma unroll
    for (int sj = 0; sj < 9; sj++) {
      bf16x2 vv = *(const bf16x2*)(v + sj * ROWP + c2);
      float w = ar[sj];
      a0 += w * b2f(vv[0]);
      a1 += w * b2f(vv[1]);
    }
    bf16x2 o;
    o[0] = f2b(a0); o[1] = f2b(a1);
    *(bf16x2*)(base + si * 1536 + c2) = o;
  }
}

// ---------------- layernorm over D=512 (bf16 in/out, fp32 g/b), one wave per 2 rows
__global__ __launch_bounds__(256) void ln_kernel(const bf16* __restrict__ in, long istride,
                                                 const float* __restrict__ g, const float* __restrict__ b,
                                                 bf16* __restrict__ out, long ostride)
{
  const int t = threadIdx.x;
  const int lane = t & 63;
  const int wave = t >> 6;
  float4 g0 = *(const float4*)(g + lane * 8);
  float4 g1 = *(const float4*)(g + lane * 8 + 4);
  float4 b0 = *(const float4*)(b + lane * 8);
  float4 b1 = *(const float4*)(b + lane * 8 + 4);
  float gg[8] = {g0.x, g0.y, g0.z, g0.w, g1.x, g1.y, g1.z, g1.w};
  float bb[8] = {b0.x, b0.y, b0.z, b0.w, b1.x, b1.y, b1.z, b1.w};
#pragma unroll
  for (int r = 0; r < 2; r++) {
    const long row = ((long)blockIdx.x * 4 + wave) * 2 + r;
    const bf16* p = in + row * istride + lane * 8;
    bf16x8 xv = *(const bf16x8*)p;
    float x[8];
    float s = 0.f;
#pragma unroll
    for (int j = 0; j < 8; j++) { x[j] = b2f(xv[j]); s += x[j]; }
#pragma unroll
    for (int off = 32; off; off >>= 1) s += __shfl_xor(s, off);
    float mean = s * (1.f / 512.f);
    float vv = 0.f;
#pragma unroll
    for (int j = 0; j < 8; j++) { float d = x[j] - mean; vv += d * d; }
#pragma unroll
    for (int off = 32; off; off >>= 1) vv += __shfl_xor(vv, off);
    float inv = rsqrtf(vv * (1.f / 512.f) + 1e-5f);
    bf16x8 o;
#pragma unroll
    for (int j = 0; j < 8; j++) o[j] = f2b((x[j] - mean) * inv * gg[j] + bb[j]);
    *(bf16x8*)(out + row * ostride + lane * 8) = o;
  }
}

// ---------------- fused embedding: blocks [0, EB): emb rows; blocks [EB, EB+seqs): raw_emb.
// emb: h[row](bf16) = adapt_w[x[row]] + adapt_b (4 rows/block).
// rawemb: raw[n](fp32) = sum_s adapt2_w[s*E + x[n,s]] + adapt2_b.
__global__ __launch_bounds__(256) void emb_fused_kernel(
    const int* __restrict__ x, const float* __restrict__ aw, const float* __restrict__ ab,
    bf16* __restrict__ h, int EB,
    const int* __restrict__ xs, const float* __restrict__ w2, const float* __restrict__ b2,
    float* __restrict__ raw)
{
  const int t = threadIdx.x;
  if ((int)blockIdx.x < EB) {
    const int lane = t & 63;
    const long row = (long)blockIdx.x * 4 + (t >> 6);
    const int ix = x[row];
    const float* w = aw + (long)ix * 512 + lane * 8;
    float4 w0 = *(const float4*)(w);
    float4 w1 = *(const float4*)(w + 4);
    float4 a0 = *(const float4*)(ab + lane * 8);
    float4 a1 = *(const float4*)(ab + lane * 8 + 4);
    float ww[8] = {w0.x, w0.y, w0.z, w0.w, w1.x, w1.y, w1.z, w1.w};
    float aa[8] = {a0.x, a0.y, a0.z, a0.w, a1.x, a1.y, a1.z, a1.w};
    bf16x8 o;
#pragma unroll
    for (int j = 0; j < 8; j++) o[j] = f2b(ww[j] + aa[j]);
    *(bf16x8*)(h + row * 512 + lane * 8) = o;
  } else {
    const long n = blockIdx.x - EB;
    const int c = t * 2;
    float a0 = b2[c], a1 = b2[c + 1];
    for (int s = 0; s < 9; s++) {
      int ix = xs[n * 9 + s];
      const float* p = w2 + ((long)(s * 631 + ix)) * 512 + c;
      a0 += p[0];
      a1 += p[1];
    }
    raw[n * 512 + c] = a0;
    raw[n * 512 + c + 1] = a1;
  }
}

// ---------------- batched weight transpose+cast: fp32 (512 x N) -> bf16 (N x 512)
struct TP { const float* src[9]; bf16* dst[9]; int n[9]; };
__global__ __launch_bounds__(256) void transpose_kernel(TP p)
{
  const int mid = blockIdx.z;
  const int N = p.n[mid];
  if ((int)blockIdx.x * 32 >= N) return;
  const float* src = p.src[mid];
  bf16* dst = p.dst[mid];
  __shared__ float tile[32][33];
  const int tx = threadIdx.x & 31;
  const int ty0 = (threadIdx.x >> 5) * 4;
  const long kb = (long)blockIdx.y * 32, nb = (long)blockIdx.x * 32;
#pragma unroll
  for (int i = 0; i < 4; i++) tile[ty0 + i][tx] = src[(kb + ty0 + i) * N + nb + tx];
  __syncthreads();
#pragma unroll
  for (int i = 0; i < 4; i++) dst[(nb + ty0 + i) * 512 + kb + tx] = f2b(tile[tx][ty0 + i]);
}

extern "C" void kernel_launch(void* const* d_in, const int* in_sizes, int n_in,
                              void* d_out, int out_size, void* d_ws, size_t ws_size,
                              hipStream_t stream)
{
  (void)in_sizes; (void)n_in; (void)out_size;
  const int*   x        = (const int*)d_in[0];
  const float* adapt2_w = (const float*)d_in[1];
  const float* adapt2_b = (const float*)d_in[2];
  const float* adapt_w  = (const float*)d_in[3];
  const float* adapt_b  = (const float*)d_in[4];
  const float* qkv_w    = (const float*)d_in[5];
  const float* qkv_b    = (const float*)d_in[6];
  const float* out_w    = (const float*)d_in[7];
  const float* out_b    = (const float*)d_in[8];
  const float* ln1_g    = (const float*)d_in[9];
  const float* ln1_b    = (const float*)d_in[10];
  const float* lin1_w   = (const float*)d_in[11];
  const float* lin1_b   = (const float*)d_in[12];
  const float* lin2_w   = (const float*)d_in[13];
  const float* lin2_b   = (const float*)d_in[14];
  const float* ln2_g    = (const float*)d_in[15];
  const float* ln2_b    = (const float*)d_in[16];
  const float* fc_w     = (const float*)d_in[17];
  const float* fc_b     = (const float*)d_in[18];
  float* outp = (float*)d_out;
  char* ws = (char*)d_ws;

  // ---- choose chunking G from ws_size (deterministic -> graph-safe)
  const long wTbytes = 6815744L;  // bf16 transposed weights
  int G = 64;
  const int cand[7] = {1, 2, 4, 8, 16, 32, 64};
  for (int i = 0; i < 7; i++) {
    long rows = 73728L / cand[i], seqs = 8192L / cand[i];
    long need = wTbytes + rows * 1024 + rows * 3072 + seqs * 2048;
    if (need <= (long)ws_size) { G = cand[i]; break; }
  }
  const long rows_c = 73728L / G;   // divisible by 192 for all candidate G
  const long seqs_c = 8192L / G;

  // ---- workspace layout
  bf16*  wT    = (bf16*)(ws);
  bf16*  h_c   = (bf16*)(ws + wTbytes);                                  // rows_c x 512 bf16
  bf16*  Qc    = (bf16*)(ws + wTbytes + rows_c * 1024);                  // rows_c x 1536 bf16
  float* raw_c = (float*)(ws + wTbytes + rows_c * 1024 + rows_c * 3072); // seqs_c x 512 fp32
  bf16* qkvT  = wT;                 // 2 x (1536 x 512)
  bf16* outT  = wT + 1572864;       // 2 x (512 x 512)
  bf16* lin1T = wT + 2097152;
  bf16* lin2T = wT + 2621440;
  bf16* fcT   = wT + 3145728;       // 512 x 512

  TP tp;
  tp.src[0] = qkv_w;           tp.dst[0] = qkvT;           tp.n[0] = 1536;
  tp.src[1] = qkv_w + 786432;  tp.dst[1] = qkvT + 786432;  tp.n[1] = 1536;
  tp.src[2] = out_w;           tp.dst[2] = outT;           tp.n[2] = 512;
  tp.src[3] = out_w + 262144;  tp.dst[3] = outT + 262144;  tp.n[3] = 512;
  tp.src[4] = lin1_w;          tp.dst[4] = lin1T;          tp.n[4] = 512;
  tp.src[5] = lin1_w + 262144; tp.dst[5] = lin1T + 262144; tp.n[5] = 512;
  tp.src[6] = lin2_w;          tp.dst[6] = lin2T;          tp.n[6] = 512;
  tp.src[7] = lin2_w + 262144; tp.dst[7] = lin2T + 262144; tp.n[7] = 512;
  tp.src[8] = fc_w;            tp.dst[8] = fcT;            tp.n[8] = 512;
  hipLaunchKernelGGL(transpose_kernel, dim3(48, 16, 9), dim3(256), 0, stream, tp);

  const bf16*  nullb = nullptr;
  const float* nullf = nullptr;
  float*       nullfo = nullptr;

  for (int g = 0; g < G; g++) {
    const long row0 = (long)g * rows_c;
    const long seq0 = (long)g * seqs_c;

    // fused emb + rawemb
    hipLaunchKernelGGL(emb_fused_kernel, dim3(rows_c / 4 + seqs_c), dim3(256), 0, stream,
        x + row0, adapt_w, adapt_b, h_c, (int)(rows_c / 4),
        x + seq0 * 9, adapt2_w, adapt2_b, raw_c);

    for (int l = 0; l < 2; l++) {
      // qkv = h @ qkv_w + qkv_b  -> Qc (rows_c x 1536)
      hipLaunchKernelGGL((gemm_kernel<6, 512, 1536, 1, false, false, false, false, true>),
          dim3(12, rows_c / 192), dim3(256), 0, stream,
          h_c, qkvT + l * 786432, qkv_b + l * 1536, nullb, nullf, Qc, nullfo);
      // attention in-place: ctx -> Qc cols [0,512)
      hipLaunchKernelGGL(attn_kernel, dim3(seqs_c), dim3(512), 0, stream, Qc);
      // hres = ctx @ out_w + out_b + h  -> Qc cols [1024,1536)
      hipLaunchKernelGGL((gemm_kernel<6, 1536, 1536, 512, false, true, false, false, true>),
          dim3(4, rows_c / 192), dim3(256), 0, stream,
          Qc, outT + l * 262144, out_b + l * 512, h_c, nullf, Qc + 1024, nullfo);
      // h1 = LN1(hres) -> Qc cols [512,1024)
      hipLaunchKernelGGL(ln_kernel, dim3(rows_c / 8), dim3(256), 0, stream,
          Qc + 1024, 1536L, ln1_g + l * 512, ln1_b + l * 512, Qc + 512, 1536L);
      // ff1 = relu(h1 @ lin1_w + lin1_b) -> Qc cols [0,512)
      hipLaunchKernelGGL((gemm_kernel<6, 1536, 1536, 1, true, false, false, false, true>),
          dim3(4, rows_c / 192), dim3(256), 0, stream,
          Qc + 512, lin1T + l * 262144, lin1_b + l * 512, nullb, nullf, Qc, nullfo);
      // hres2 = ff1 @ lin2_w + lin2_b + h1 -> h_c
      hipLaunchKernelGGL((gemm_kernel<6, 1536, 512, 1536, false, true, false, false, true>),
          dim3(4, rows_c / 192), dim3(256), 0, stream,
          Qc, lin2T + l * 262144, lin2_b + l * 512, Qc + 512, nullf, h_c, nullfo);
      // h = LN2(hres2) in-place on h_c
      hipLaunchKernelGGL(ln_kernel, dim3(rows_c / 8), dim3(256), 0, stream,
          h_c, 512L, ln2_g + l * 512, ln2_b + l * 512, h_c, 512L);
    }

    // out(fp32) = raw * (1 + relu(cls @ fc_w + fc_b)); cls rows at stride 4608 in h_c
    hipLaunchKernelGGL((gemm_kernel<4, 4608, 512, 1, false, false, true, true, false>),
        dim3(4, seqs_c / 128), dim3(256), 0, stream,
        h_c, fcT, fc_b, nullb, raw_c, (bf16*)nullptr, outp + seq0 * 512);
  }
}